// Round 10
// baseline (318.676 us; speedup 1.0000x reference)
//
#include <hip/hip_runtime.h>

// GCN forward: 3x GCNConv (128->64->64->2) + linear head (2->16).
// N=100000 nodes, E=1600000 edges (+self-loops handled analytically).
// Preprocessing: two-level LDS bucket sort. Aggregation: atomic-free
// FULL-WAVE segment-sum gathers (lane = channel) over int16 rows with
// per-row scales; TWO nodes per wave interleaved.
// Round 26 (dispatch consolidation; kernel bodies byte-identical to r25):
//  - Budget residual ~115us is stable across rounds and matches ~10us x
//    11 dispatches of launch/serialization overhead. This round: 11 -> 9.
//  - k_init0 MERGED into k_prep0 (blocks 0-23 = W fragments, rest = ccnt
//    zero + fmt detect).
//  - k_cscan ELIMINATED: k_coarse's LAST block (device-scope done counter +
//    threadfence; ccnt read via atomicAdd(p,0) -- XCD-safe) computes the
//    512-slot exclusive scan in LDS and writes cstart.
//  - Delta vs prediction disambiguates the gap theory for next round.
// r25 verified state: 303.6us total; seg1f top at 48.3 (1.87 TB/s random-row
// ceiling); k_seg ~46; gemmM ~15 direct-load; gemmM64 ~12; MFMA f16
// split-precision path HW-verified (absmax 4.88e-4 = bf16 comparison floor).
// REGIME NOTE (r20 measured): gather kernels are RANDOM-ROW-TRAFFIC bound
// (~1.4-1.8 TB/s fabric on 128B rows); int16 rows ARE the bandwidth opt.
// In-flight analysis (r9): not latency-bound -- deeper unroll won't help.
// BANNED (measured failures): half-wave/2-rows-per-load gather (~3e-3 absmax,
// r7-9/11); SGPR-indexed rs[] (s_load thrash, r13); LDS float atomicAdd
// (CAS storm, r15); LDS row pitch not 0 mod 16B in float4 tiles (r17);
// 64-entry per-lane VGPR arrays in gather kernels (occupancy halved, r17);
// persistent grid-stride gather blocks (load imbalance + VGPR, r19);
// fp32 pre-scaled gather rows (2x traffic on traffic-bound GATHER, r20);
// partial LDS staging loops -- verify counts against buffer size (r22);
// growing the workspace footprint past the verified layout (r24).
// dis[] pre-folded: T'[v]=dis[v]*t[v] => O[i]=dis[i]*(T'[i]+sum T'[s])+b.

#define NF 128
#define NH 64
#define NPB 256      // nodes per coarse bucket (bucket = dst >> 8)
#define MAXNB 512    // max coarse buckets (N < 131072, matches 17-bit src pack)
#define CAP 6144     // max edges per coarse bucket (mean 4096, >30 sigma)
#define A1G 1024     // grid for coarse count/scatter (must match between them)

typedef _Float16 half8 __attribute__((ext_vector_type(8)));
typedef float f32x4 __attribute__((ext_vector_type(4)));

// Merged W-fragment precompute + init.
// Blocks 0-15:  W0 fragments (128x64). Blocks 16-23: W1 fragments (64x64).
// Blocks >=24: zero ccnt (incl. done counter) + detect int64/int32 layout.
// Fragment entry: k = kc*32 + (lane>>4)*8 + j, col = ct*16 + (lane&15).
__global__ void k_prep0(const float* __restrict__ W0, const float* __restrict__ W1,
                        short* __restrict__ wf0, short* __restrict__ wf1,
                        const int* __restrict__ ei, int* __restrict__ fmt,
                        int* __restrict__ ccnt, int nb16) {
    int b = blockIdx.x;
    int t = threadIdx.x;
    if (b < 24) {
        int lane = t & 63;
        int j0 = (t >> 6) * 2;
        const float* W = (b < 16) ? W0 : W1;
        int bb = (b < 16) ? b : (b - 16);
        short* wf = (b < 16) ? wf0 : wf1;
        int lohalf = (b < 16) ? 8192 : 4096;
        int kc = bb >> 2, ct = bb & 3;
        #pragma unroll
        for (int jj = 0; jj < 2; ++jj) {
            int j = j0 + jj;
            int k = kc * 32 + (lane >> 4) * 8 + j;
            int col = ct * 16 + (lane & 15);
            float w = W[k * NH + col];
            _Float16 h = (_Float16)w;
            _Float16 l = (_Float16)(w - (float)h);
            int idx = (bb * 64 + lane) * 8 + j;
            wf[idx] = *(short*)&h;
            wf[idx + lohalf] = *(short*)&l;
        }
        return;
    }
    int i = (b - 24) * 256 + t;
    if (i < nb16) ccnt[i] = 0;
    if (i == 0) {
        int f = 1;
        #pragma unroll
        for (int k = 1; k < 32; k += 2) if (ei[k] != 0) f = 0;
        *fmt = f;   // 1 => int64 (stride 2 in int32 words), 0 => int32
    }
}

// Coarse count + (last block) exclusive scan -> cstart.
// LDS histogram per block, ONE padded global atomic per bucket per block.
// Last block (device-scope done counter) scans ccnt into cstart, replacing
// the separate k_cscan dispatch. ccnt read via atomicAdd(p,0) (XCD-safe).
__global__ void __launch_bounds__(256) k_coarse(
        const int* __restrict__ ei, const int* __restrict__ fmt,
        int* __restrict__ ccnt, int* __restrict__ blockbase,
        int* __restrict__ done, int* __restrict__ cstart, int E, int NB) {
    __shared__ int h[MAXNB];
    __shared__ int lastflag;
    int sh = *fmt;
    for (int i = threadIdx.x; i < NB; i += 256) h[i] = 0;
    __syncthreads();
    for (long long e = (long long)blockIdx.x * 256 + threadIdx.x; e < E;
         e += (long long)A1G * 256) {
        int d = ei[(long long)(E + e) << sh];
        atomicAdd(&h[d >> 8], 1);
    }
    __syncthreads();
    for (int b = threadIdx.x; b < NB; b += 256) {
        int c = h[b];
        int base = (c > 0) ? atomicAdd(&ccnt[b * 16], c) : 0;
        blockbase[(long long)blockIdx.x * NB + b] = base;
    }
    __syncthreads();
    if (threadIdx.x == 0) {
        __threadfence();
        int old = atomicAdd(done, 1);
        lastflag = (old == A1G - 1) ? 1 : 0;
    }
    __syncthreads();
    if (!lastflag) return;
    __threadfence();
    // ---- last block: 512-slot exclusive scan of ccnt -> cstart
    __shared__ int s[512];
    int t = threadIdx.x;
    int v0 = (t < NB) ? atomicAdd(&ccnt[t * 16], 0) : 0;
    int v1 = (t + 256 < NB) ? atomicAdd(&ccnt[(t + 256) * 16], 0) : 0;
    s[t] = v0;
    s[t + 256] = v1;
    __syncthreads();
    for (int off = 1; off < 512; off <<= 1) {
        int u0 = s[t] + ((t >= off) ? s[t - off] : 0);
        int i1 = t + 256;
        int u1 = s[i1] + s[i1 - off];     // i1 >= 256 >= off always
        __syncthreads();
        s[t] = u0;
        s[i1] = u1;
        __syncthreads();
    }
    if (t < NB) cstart[t] = s[t] - v0;
    if (t + 256 < NB) cstart[t + 256] = s[t + 256] - v1;
}

// Coarse scatter: same grid-stride partition as k_coarse, so this block's
// per-bucket totals equal its reservation. Edge packed as src|(dst&255)<<17.
__global__ void __launch_bounds__(256) k_cscatter(
        const int* __restrict__ ei, const int* __restrict__ fmt,
        const int* __restrict__ cstart, const int* __restrict__ blockbase,
        int* __restrict__ pairs, int E, int NB) {
    __shared__ int h[MAXNB];
    __shared__ int bb[MAXNB];
    int sh = *fmt;
    for (int i = threadIdx.x; i < NB; i += 256) {
        h[i] = 0;
        bb[i] = cstart[i] + blockbase[(long long)blockIdx.x * NB + i];
    }
    __syncthreads();
    for (long long e = (long long)blockIdx.x * 256 + threadIdx.x; e < E;
         e += (long long)A1G * 256) {
        int s = ei[(long long)e << sh];
        int d = ei[(long long)(E + e) << sh];
        int b = d >> 8;
        int r = atomicAdd(&h[b], 1);
        pairs[bb[b] + r] = s | ((d & 255) << 17);
    }
}

// Fine sort: one block per coarse bucket, entirely in LDS. Emits cnt/start/dis
// (coalesced) and esrc (scatter within the bucket's contiguous window).
__global__ void __launch_bounds__(256) k_bucket(
        const int* __restrict__ pairs, const int* __restrict__ ccnt,
        const int* __restrict__ cstart, int* __restrict__ esrc,
        int* __restrict__ cnt, int* __restrict__ start, float* __restrict__ dis,
        int N) {
    __shared__ int words[CAP];
    __shared__ unsigned char rk[CAP];
    __shared__ int h[NPB];
    __shared__ int hs[NPB];
    int b = blockIdx.x;
    int cs = cstart[b];
    int ec = ccnt[b * 16];
    if (ec > CAP) ec = CAP;          // memory-safety clamp (P ~ 0 for uniform dst)
    int t = threadIdx.x;
    for (int i = t; i < ec; i += 256) words[i] = pairs[cs + i];
    h[t] = 0;
    __syncthreads();
    for (int i = t; i < ec; i += 256) {
        int ld = words[i] >> 17;
        rk[i] = (unsigned char)atomicAdd(&h[ld], 1);
    }
    __syncthreads();
    int c = h[t];
    hs[t] = c;
    __syncthreads();
    for (int off = 1; off < 256; off <<= 1) {
        int v = hs[t];
        int u = (t >= off) ? hs[t - off] : 0;
        __syncthreads();
        hs[t] = v + u;               // inclusive scan
        __syncthreads();
    }
    int node = b * NPB + t;
    if (node < N) {
        cnt[node] = c;
        start[node] = cs + hs[t] - c;
        dis[node] = rsqrtf(1.0f + (float)c);   // degree includes self-loop
    }
    for (int i = t; i < ec; i += 256) {
        int w = words[i];
        int ld = w >> 17;
        esrc[cs + (hs[ld] - h[ld]) + rk[i]] = w & 0x1FFFF;
    }
}

// Shared MFMA epilogue: dis-scale + rowwise int16 quant + store.
// Lane holds D[(lane>>4)*4 + r][ct*16 + (lane&15)] for ct=0..3 (m89 map).
#define GEMM_EPILOGUE                                                         \
    int rb = (int)rowbase + wid * 16 + (lane >> 4) * 4;                       \
    float drs[4];                                                             \
    drs[0] = (rb + 0 < n) ? dis[rb + 0] : 0.0f;                               \
    drs[1] = (rb + 1 < n) ? dis[rb + 1] : 0.0f;                               \
    drs[2] = (rb + 2 < n) ? dis[rb + 2] : 0.0f;                               \
    drs[3] = (rb + 3 < n) ? dis[rb + 3] : 0.0f;                               \
    const float ks = 1.0f / 32767.0f;                                         \
    int cb = lane & 15;                                                       \
    _Pragma("unroll")                                                         \
    for (int r = 0; r < 4; ++r) {                                             \
        float v0 = acc0[r] * drs[r];                                          \
        float v1 = acc1[r] * drs[r];                                          \
        float v2 = acc2[r] * drs[r];                                          \
        float v3 = acc3[r] * drs[r];                                          \
        float m = fmaxf(fmaxf(fabsf(v0), fabsf(v1)), fmaxf(fabsf(v2), fabsf(v3))); \
        m = fmaxf(m, __shfl_xor(m, 1, 64));                                   \
        m = fmaxf(m, __shfl_xor(m, 2, 64));                                   \
        m = fmaxf(m, __shfl_xor(m, 4, 64));                                   \
        m = fmaxf(m, __shfl_xor(m, 8, 64));                                   \
        float ir = 32767.0f / fmaxf(m, 1e-20f);                               \
        int rowg = rb + r;                                                    \
        if (rowg < n) {                                                       \
            long long base = (long long)rowg * NH;                            \
            T16[base + 0  + cb] = (short)__float2int_rn(v0 * ir);             \
            T16[base + 16 + cb] = (short)__float2int_rn(v1 * ir);             \
            T16[base + 32 + cb] = (short)__float2int_rn(v2 * ir);             \
            T16[base + 48 + cb] = (short)__float2int_rn(v3 * ir);             \
            if (cb == 0) rs[rowg] = m * ks;                                   \
        }                                                                     \
    }

// Convert lane's 8 A-floats to f16 hi/lo fragments.
#define CVT_AFRAG(xa, xb4)                                                    \
    half8 ah, al;                                                             \
    {                                                                         \
        float xv[8] = {xa.x, xa.y, xa.z, xa.w, xb4.x, xb4.y, xb4.z, xb4.w};   \
        _Pragma("unroll")                                                     \
        for (int e = 0; e < 8; ++e) {                                         \
            _Float16 h = (_Float16)xv[e];                                     \
            ah[e] = h;                                                        \
            al[e] = (_Float16)(xv[e] - (float)h);                             \
        }                                                                     \
    }

#define MFMA3(ACC, SETIDX, LOHALF)                                            \
    {                                                                         \
        const half8 bh = *(const half8*)&Wf[((SETIDX) * 64 + lane) * 8];      \
        const half8 bl = *(const half8*)&Wf[((SETIDX) * 64 + lane) * 8 + (LOHALF)]; \
        ACC = __builtin_amdgcn_mfma_f32_16x16x32_f16(ah, bh, ACC, 0, 0, 0);   \
        ACC = __builtin_amdgcn_mfma_f32_16x16x32_f16(ah, bl, ACC, 0, 0, 0);   \
        ACC = __builtin_amdgcn_mfma_f32_16x16x32_f16(al, bh, ACC, 0, 0, 0);   \
    }

// Layer-0 transform on MATRIX CORES, DIRECT-LOAD A: T16 = quant(dis*(X@W0)).
// 64 rows/block, 4 waves, 16 rows/wave; lane reads its 32B A-slice per kc
// straight from global (4 lanes share each 128B line; X read exactly once).
// LDS = Wf only (32KB = 2048 int4, staged once) => 5 blocks/CU, ONE barrier.
__global__ void __launch_bounds__(256) k_gemmM(
        const float* __restrict__ X, const short* __restrict__ wfrag,
        const float* __restrict__ dis, short* __restrict__ T16,
        float* __restrict__ rs, int n) {
    __shared__ __align__(16) short Wf[16384];   // [hi 8192][lo 8192]
    int tid = threadIdx.x;
    {
        const int4* src = (const int4*)wfrag;
        int4* dst = (int4*)Wf;
        #pragma unroll
        for (int u = 0; u < 8; ++u) dst[tid + u * 256] = src[tid + u * 256];
    }
    __syncthreads();
    long long rowbase = (long long)blockIdx.x * 64;
    int lane = tid & 63;
    int wid = tid >> 6;
    int row = (int)rowbase + wid * 16 + (lane & 15);
    bool ok = row < n;
    const float* xb = X + (long long)row * NF + (lane >> 4) * 8;
    f32x4 acc0 = {0,0,0,0}, acc1 = {0,0,0,0}, acc2 = {0,0,0,0}, acc3 = {0,0,0,0};
    #pragma unroll
    for (int kc = 0; kc < 4; ++kc) {
        float4 xa = ok ? *(const float4*)(xb + kc * 32)
                       : make_float4(0.f, 0.f, 0.f, 0.f);
        float4 xc = ok ? *(const float4*)(xb + kc * 32 + 4)
                       : make_float4(0.f, 0.f, 0.f, 0.f);
        CVT_AFRAG(xa, xc)
        MFMA3(acc0, kc * 4 + 0, 8192)
        MFMA3(acc1, kc * 4 + 1, 8192)
        MFMA3(acc2, kc * 4 + 2, 8192)
        MFMA3(acc3, kc * 4 + 3, 8192)
    }
    GEMM_EPILOGUE
}

// Layer-1 transform on MATRIX CORES: T16 = quant(dis*(H0@W1)), H0 fp32 [N,64]
// streamed (coalesced GEMM operand -- r20's random-gather fp32 ban N/A).
// 24 MFMA/wave; LDS = Wf1 16KB (1024 int4).
__global__ void __launch_bounds__(256) k_gemmM64(
        const float* __restrict__ H, const short* __restrict__ wfrag,
        const float* __restrict__ dis, short* __restrict__ T16,
        float* __restrict__ rs, int n) {
    __shared__ __align__(16) short Wf[8192];    // [hi 4096][lo 4096]
    int tid = threadIdx.x;
    {
        const int4* src = (const int4*)wfrag;
        int4* dst = (int4*)Wf;
        #pragma unroll
        for (int u = 0; u < 4; ++u) dst[tid + u * 256] = src[tid + u * 256];
    }
    __syncthreads();
    long long rowbase = (long long)blockIdx.x * 64;
    int lane = tid & 63;
    int wid = tid >> 6;
    int row = (int)rowbase + wid * 16 + (lane & 15);
    bool ok = row < n;
    const float* hb = H + (long long)row * NH + (lane >> 4) * 8;
    f32x4 acc0 = {0,0,0,0}, acc1 = {0,0,0,0}, acc2 = {0,0,0,0}, acc3 = {0,0,0,0};
    #pragma unroll
    for (int kc = 0; kc < 2; ++kc) {
        float4 xa = ok ? *(const float4*)(hb + kc * 32)
                       : make_float4(0.f, 0.f, 0.f, 0.f);
        float4 xc = ok ? *(const float4*)(hb + kc * 32 + 4)
                       : make_float4(0.f, 0.f, 0.f, 0.f);
        CVT_AFRAG(xa, xc)
        MFMA3(acc0, kc * 4 + 0, 4096)
        MFMA3(acc1, kc * 4 + 1, 4096)
        MFMA3(acc2, kc * 4 + 2, 4096)
        MFMA3(acc3, kc * 4 + 3, 4096)
    }
    GEMM_EPILOGUE
}

// One A-edge / B-edge step: readlane word+scale bits, saddr int16 load, fma.
#define EDGE_A(J) {                                                           \
    int s_ = __builtin_amdgcn_readlane(sA, (J));                              \
    float f_ = __int_as_float(__builtin_amdgcn_readlane(fAb, (J)));           \
    accA = fmaf(f_, (float)(T + s_ * NH)[lane], accA); }
#define EDGE_B(J) {                                                           \
    int s_ = __builtin_amdgcn_readlane(sB, (J));                              \
    float f_ = __int_as_float(__builtin_amdgcn_readlane(fBb, (J)));           \
    accB = fmaf(f_, (float)(T + s_ * NH)[lane], accB); }

// Full-wave gather, TWO nodes per wave (A,B) with interleaved batches:
// the two batch prologues (esrc load + rs vector-gather) are independent
// chains and overlap; inner loop interleaves 4 A-edges + 4 B-edges.
#define SEG_GATHER2                                                           \
    int lane = threadIdx.x & 63;                                              \
    int na = blockIdx.x * 8 + (threadIdx.x >> 6) * 2;                         \
    int nb_ = na + 1;                                                         \
    if (na >= n) return;                                                      \
    bool hasB = (nb_ < n);                                                    \
    float dia = dis[na];                                                      \
    float dib = hasB ? dis[nb_] : 0.0f;                                       \
    int ga = cnt[na], sta = start[na];                                        \
    int gb = hasB ? cnt[nb_] : 0;                                             \
    int stb = hasB ? start[nb_] : 0;                                          \
    float accA = rs[na] * (float)T[na * NH + lane];                           \
    float accB = hasB ? rs[nb_] * (float)T[nb_ * NH + lane] : 0.0f;           \
    int gmax = ga > gb ? ga : gb;                                             \
    for (int base = 0; base < gmax; base += 64) {                             \
        int ma = ga - base; ma = ma < 0 ? 0 : (ma > 64 ? 64 : ma);            \
        int mb = gb - base; mb = mb < 0 ? 0 : (mb > 64 ? 64 : mb);            \
        int sA = 0, sB = 0; float fA = 0.0f, fB = 0.0f;                       \
        if (lane < ma) { sA = esrc[sta + base + lane]; fA = rs[sA]; }         \
        if (lane < mb) { sB = esrc[stb + base + lane]; fB = rs[sB]; }         \
        int fAb = __float_as_int(fA), fBb = __float_as_int(fB);               \
        int mmin = ma < mb ? ma : mb;                                         \
        int j = 0;                                                            \
        for (; j + 3 < mmin; j += 4) {                                        \
            EDGE_A(j + 0) EDGE_B(j + 0)                                       \
            EDGE_A(j + 1) EDGE_B(j + 1)                                       \
            EDGE_A(j + 2) EDGE_B(j + 2)                                       \
            EDGE_A(j + 3) EDGE_B(j + 3)                                       \
        }                                                                     \
        int jA = j, jB = j;                                                   \
        for (; jA + 3 < ma; jA += 4) {                                        \
            EDGE_A(jA + 0) EDGE_A(jA + 1) EDGE_A(jA + 2) EDGE_A(jA + 3)       \
        }                                                                     \
        for (; jA < ma; ++jA) EDGE_A(jA)                                      \
        for (; jB + 3 < mb; jB += 4) {                                        \
            EDGE_B(jB + 0) EDGE_B(jB + 1) EDGE_B(jB + 2) EDGE_B(jB + 3)       \
        }                                                                     \
        for (; jB < mb; ++jB) EDGE_B(jB)                                      \
    }

// Layer-0 aggregation: h0 = dia*acc + b0 written as fp32 (streamed GEMM
// operand for k_gemmM64). r2-verified form (~46us, VALUBusy 73%, occ 72%).
__global__ void __launch_bounds__(256) k_seg(
        const short* __restrict__ T, const float* __restrict__ rs,
        const int* __restrict__ esrc, const int* __restrict__ start,
        const int* __restrict__ cnt, const float* __restrict__ dis,
        const float* __restrict__ b0, float* __restrict__ O, int n) {
    SEG_GATHER2
    float bv = b0[lane];
    O[(long long)na * NH + lane] = dia * accA + bv;
    if (hasB) O[(long long)nb_ * NH + lane] = dib * accB + bv;
}

// Layer-1 + fused layer-2 transform for both nodes: z1[c]=di*acc+b1[c];
// t=tanh(z1); t2 = di*(t @ W2) via 6-step full-wave butterfly (per node).
__global__ void __launch_bounds__(256) k_seg1f(
        const short* __restrict__ T, const float* __restrict__ rs,
        const int* __restrict__ esrc, const int* __restrict__ start,
        const int* __restrict__ cnt, const float* __restrict__ dis,
        const float* __restrict__ b1, const float* __restrict__ W2,
        float2* __restrict__ t2, int n) {
    SEG_GATHER2
    float bv = b1[lane];
    float2 w = ((const float2*)W2)[lane];   // W2[lane][0], W2[lane][1]
    float tA = tanhf(dia * accA + bv);
    float p0 = tA * w.x, p1 = tA * w.y;
    float tB = hasB ? tanhf(dib * accB + bv) : 0.0f;
    float q0 = tB * w.x, q1 = tB * w.y;
    #pragma unroll
    for (int msk = 32; msk; msk >>= 1) {
        p0 += __shfl_xor(p0, msk, 64);
        p1 += __shfl_xor(p1, msk, 64);
        q0 += __shfl_xor(q0, msk, 64);
        q1 += __shfl_xor(q1, msk, 64);
    }
    if (lane == 0) {
        t2[na] = make_float2(dia * p0, dia * p1);
        if (hasB) t2[nb_] = make_float2(dib * q0, dib * q1);
    }
}

// Fused layer-2 aggregation + head, 16 LANES PER NODE (4 nodes/wave):
// lane-parallel edge loads, 4-step shfl_xor reduce, lanes 0-3 write the
// 16 output channels.
__global__ void __launch_bounds__(256) k_seg2f(
        const float2* __restrict__ T2, const int* __restrict__ esrc,
        const int* __restrict__ start, const int* __restrict__ cnt,
        const float* __restrict__ dis, const float* __restrict__ b2,
        const float* __restrict__ Wc, const float* __restrict__ bc,
        float* __restrict__ out, float* __restrict__ emb, int n) {
    int lane = threadIdx.x & 63;
    int sub = lane >> 4;           // node slot within the wave
    int sl = lane & 15;            // lane within the node's 16-lane group
    int i = blockIdx.x * 16 + (threadIdx.x >> 6) * 4 + sub;
    if (i >= n) return;            // whole 16-lane group exits together
    float di = dis[i];
    int g = cnt[i], st = start[i];
    float a0 = 0.0f, a1 = 0.0f;
    for (int j = sl; j < g; j += 16) {
        float2 v = T2[esrc[st + j]];
        a0 += v.x; a1 += v.y;
    }
    if (sl == 0) {
        float2 s = T2[i];
        a0 += s.x; a1 += s.y;
    }
    #pragma unroll
    for (int msk = 8; msk; msk >>= 1) {
        a0 += __shfl_xor(a0, msk, 64);
        a1 += __shfl_xor(a1, msk, 64);
    }
    float e0 = tanhf(a0 * di + b2[0]);
    float e1 = tanhf(a1 * di + b2[1]);
    if (sl == 0) *(float2*)&emb[(long long)i * 2] = make_float2(e0, e1);
    if (sl < 4) {
        int c = sl * 4;
        float4 o;
        o.x = e0 * Wc[c + 0] + e1 * Wc[16 + c + 0] + bc[c + 0];
        o.y = e0 * Wc[c + 1] + e1 * Wc[16 + c + 1] + bc[c + 1];
        o.z = e0 * Wc[c + 2] + e1 * Wc[16 + c + 2] + bc[c + 2];
        o.w = e0 * Wc[c + 3] + e1 * Wc[16 + c + 3] + bc[c + 3];
        *(float4*)&out[(long long)i * 16 + c] = o;
    }
}

extern "C" void kernel_launch(void* const* d_in, const int* in_sizes, int n_in,
                              void* d_out, int out_size, void* d_ws, size_t ws_size,
                              hipStream_t stream) {
    const float* x  = (const float*)d_in[0];
    const int*   ei = (const int*)  d_in[1];
    const float* W0 = (const float*)d_in[2];
    const float* b0 = (const float*)d_in[3];
    const float* W1 = (const float*)d_in[4];
    const float* b1 = (const float*)d_in[5];
    const float* W2 = (const float*)d_in[6];
    const float* b2 = (const float*)d_in[7];
    const float* Wc = (const float*)d_in[8];
    const float* bc = (const float*)d_in[9];

    int N = in_sizes[0] / NF;
    int E = in_sizes[1] / 2;
    int NB = (N + NPB - 1) / NPB;   // 391 for N=100000 (must be <= MAXNB)

    float* out = (float*)d_out;                    // [N,16]
    float* emb = out + (long long)N * 16;          // [N,2]

    // workspace (UNCHANGED footprint vs verified rounds):
    //   T16a[N*64 int16 = 12.8MB] | Bb[N*64 fp32 = 25.6MB] |
    //   dis[N] | rs_a[N] | cnt[N] | start[N] | esrc[E] | fmt
    // wf0 (32KB) + wf1 (16KB) live at the START OF d_out: out is written
    // only by the final k_seg2f (which overwrites every element); fragments
    // are consumed by gemmM/gemmM64 before that. Zero footprint growth.
    // done counter = ccnt[NB*16] (zeroed by k_prep0 via nb16+16).
    // Flow: gemmM: x->T16a.  k_seg: T16a->Bb (h0).  gemmM64: Bb->T16a.
    // seg1f: T16a->t2 (t2 overlays dead Bb).  Prep scratch overlays T16a.
    short*  T16a = (short*)d_ws;
    float*  Bb   = (float*)((char*)d_ws + (long long)N * NH * 2);
    float*  dis  = (float*)((char*)d_ws + (long long)N * NH * 2 + (long long)N * NH * 4);
    float*  rs_a = dis + N;
    int*    cnt   = (int*)(rs_a + N);
    int*    start = cnt + N;
    int*    esrc  = start + N;
    int*    fmt   = esrc + E;
    short*  wf0   = (short*)d_out;                 // 16384 shorts (32KB)
    short*  wf1   = wf0 + 16384;                   // 8192 shorts (16KB)
    float2* t2    = (float2*)Bb;                   // overlays dead Bb

    int* pairs     = (int*)d_ws;                       // E ints (overlay T16a)
    int* blockbase = pairs + E;                        // A1G * NB
    int* ccnt      = blockbase + (long long)A1G * NB;  // NB*16 + done pad
    int* cstart    = ccnt + NB * 16 + 16;              // NB
    int* done      = ccnt + NB * 16;                   // 1 int (padded)

    int nb_g  = (N + 63) / 64;
    int nb_s2 = (N + 7) / 8;
    int nb_2f = (N + 15) / 16;
    int nb16  = NB * 16 + 16;                          // incl. done counter
    int nb_i0 = (nb16 + 255) / 256;

    // merged: W fragments + ccnt/done zero + fmt detect
    k_prep0   <<<24 + nb_i0, 256, 0, stream>>>(W0, W1, wf0, wf1, ei, fmt,
                                               ccnt, nb16);
    // coarse count + last-block scan -> cstart (k_cscan eliminated)
    k_coarse  <<<A1G, 256, 0, stream>>>(ei, fmt, ccnt, blockbase, done,
                                        cstart, E, NB);
    k_cscatter<<<A1G, 256, 0, stream>>>(ei, fmt, cstart, blockbase, pairs, E, NB);
    k_bucket  <<<NB, 256, 0, stream>>>(pairs, ccnt, cstart, esrc, cnt, start, dis, N);

    // layer 0: MFMA gemm (direct-load A) + rowwise int16 quant
    k_gemmM   <<<nb_g, 256, 0, stream>>>(x, wf0, dis, T16a, rs_a, N);

    // layer-0 gather -> h0 fp32 (streamed operand)
    k_seg     <<<nb_s2, 256, 0, stream>>>(T16a, rs_a, esrc, start, cnt, dis, b0,
                                          Bb, N);

    // layer-1 transform: MFMA gemm64 (Bb -> T16a, rs_a overwritten)
    k_gemmM64 <<<nb_g, 256, 0, stream>>>(Bb, wf1, dis, T16a, rs_a, N);

    // layer 1 gather + fused layer-2 transform (tanh + @W2 in epilogue)
    k_seg1f   <<<nb_s2, 256, 0, stream>>>(T16a, rs_a, esrc, start, cnt, dis, b1,
                                          W2, t2, N);

    // layer-2 aggregation + head (16 lanes per node)
    k_seg2f   <<<nb_2f, 256, 0, stream>>>(t2, esrc, start, cnt, dis, b2, Wc, bc,
                                          out, emb, N);
}

// Round 11
// 276.904 us; speedup vs baseline: 1.1509x; 1.1509x over previous
//
#include <hip/hip_runtime.h>

// GCN forward: 3x GCNConv (128->64->64->2) + linear head (2->16).
// N=100000 nodes, E=1600000 edges (+self-loops handled analytically).
// Preprocessing: two-level LDS bucket sort. Aggregation: atomic-free
// FULL-WAVE segment-sum gathers (lane = channel) over int16 rows with
// per-row scales; TWO nodes per wave interleaved.
// Round 27:
//  - REVERTED r26's last-block-scan k_coarse (+13us: fence/done-atomic/
//    one-block scan tail). k_cscan restored as its own dispatch. r26 also
//    REFUTED the 10us/dispatch launch-overhead theory (removing 2 saved ~0;
//    true overhead ~4.5us/dispatch). Re-tally: PREP was the hidden cost:
//    coarse ~47 + cscatter ~45 + bucket ~25 ~= 120us of 303.
//  - k_coarse/k_cscatter DE-LATENCYFIED (first counters: VALUBusy 0.8%,
//    290GB/s, pure stall): A1G 1024->512 (atomic queue per ccnt address
//    halved; 12 iters/thread) + x4 unrolled edge loops (4 independent
//    loads in flight). One mechanism: more MLP per thread.
//  - k_prep0 (init merged into W-fragment precompute) kept from r26.
// r25 verified: 303.6us; seg1f 48.3 top (1.87 TB/s random-row ceiling);
// k_seg ~46; gemmM ~15; gemmM64 ~12; MFMA f16 split path HW-verified.
// REGIME NOTE (r20): gather kernels are RANDOM-ROW-TRAFFIC bound
// (~1.4-1.8 TB/s on 128B rows); int16 rows ARE the bandwidth opt.
// BANNED (measured failures): half-wave/2-rows-per-load gather (~3e-3 absmax,
// r7-9/11); SGPR-indexed rs[] (r13); LDS float atomicAdd (r15); LDS row
// pitch not 0 mod 16B in float4 tiles (r17); 64-entry per-lane VGPR arrays
// in gather kernels (r17); persistent grid-stride gather blocks (r19);
// fp32 pre-scaled gather rows (r20); partial LDS staging loops (r22);
// growing workspace footprint (r24); last-block-scan merge in k_coarse (r26).
// dis[] pre-folded: T'[v]=dis[v]*t[v] => O[i]=dis[i]*(T'[i]+sum T'[s])+b.

#define NF 128
#define NH 64
#define NPB 256      // nodes per coarse bucket (bucket = dst >> 8)
#define MAXNB 512    // max coarse buckets (N < 131072, matches 17-bit src pack)
#define CAP 6144     // max edges per coarse bucket (mean 4096, >30 sigma)
#define A1G 512      // grid for coarse count/scatter (must match between them)

typedef _Float16 half8 __attribute__((ext_vector_type(8)));
typedef float f32x4 __attribute__((ext_vector_type(4)));

// Merged W-fragment precompute + init.
// Blocks 0-15:  W0 fragments (128x64). Blocks 16-23: W1 fragments (64x64).
// Blocks >=24: zero ccnt + detect int64/int32 layout.
// Fragment entry: k = kc*32 + (lane>>4)*8 + j, col = ct*16 + (lane&15).
__global__ void k_prep0(const float* __restrict__ W0, const float* __restrict__ W1,
                        short* __restrict__ wf0, short* __restrict__ wf1,
                        const int* __restrict__ ei, int* __restrict__ fmt,
                        int* __restrict__ ccnt, int nb16) {
    int b = blockIdx.x;
    int t = threadIdx.x;
    if (b < 24) {
        int lane = t & 63;
        int j0 = (t >> 6) * 2;
        const float* W = (b < 16) ? W0 : W1;
        int bb = (b < 16) ? b : (b - 16);
        short* wf = (b < 16) ? wf0 : wf1;
        int lohalf = (b < 16) ? 8192 : 4096;
        int kc = bb >> 2, ct = bb & 3;
        #pragma unroll
        for (int jj = 0; jj < 2; ++jj) {
            int j = j0 + jj;
            int k = kc * 32 + (lane >> 4) * 8 + j;
            int col = ct * 16 + (lane & 15);
            float w = W[k * NH + col];
            _Float16 h = (_Float16)w;
            _Float16 l = (_Float16)(w - (float)h);
            int idx = (bb * 64 + lane) * 8 + j;
            wf[idx] = *(short*)&h;
            wf[idx + lohalf] = *(short*)&l;
        }
        return;
    }
    int i = (b - 24) * 256 + t;
    if (i < nb16) ccnt[i] = 0;
    if (i == 0) {
        int f = 1;
        #pragma unroll
        for (int k = 1; k < 32; k += 2) if (ei[k] != 0) f = 0;
        *fmt = f;   // 1 => int64 (stride 2 in int32 words), 0 => int32
    }
}

// Coarse count: LDS histogram per block (x4-unrolled edge loop: 4 independent
// loads in flight -- r26 counters showed VALUBusy 0.8% = pure load stall),
// then ONE padded global atomic per bucket per block.
__global__ void __launch_bounds__(256) k_coarse(
        const int* __restrict__ ei, const int* __restrict__ fmt,
        int* __restrict__ ccnt, int* __restrict__ blockbase, int E, int NB) {
    __shared__ int h[MAXNB];
    int sh = *fmt;
    for (int i = threadIdx.x; i < NB; i += 256) h[i] = 0;
    __syncthreads();
    const long long S = (long long)A1G * 256;
    long long e = (long long)blockIdx.x * 256 + threadIdx.x;
    for (; e + 3 * S < E; e += 4 * S) {
        int d0 = ei[(long long)(E + e) << sh];
        int d1 = ei[(long long)(E + e + S) << sh];
        int d2 = ei[(long long)(E + e + 2 * S) << sh];
        int d3 = ei[(long long)(E + e + 3 * S) << sh];
        atomicAdd(&h[d0 >> 8], 1);
        atomicAdd(&h[d1 >> 8], 1);
        atomicAdd(&h[d2 >> 8], 1);
        atomicAdd(&h[d3 >> 8], 1);
    }
    for (; e < E; e += S) {
        int d = ei[(long long)(E + e) << sh];
        atomicAdd(&h[d >> 8], 1);
    }
    __syncthreads();
    for (int b = threadIdx.x; b < NB; b += 256) {
        int c = h[b];
        int base = (c > 0) ? atomicAdd(&ccnt[b * 16], c) : 0;
        blockbase[(long long)blockIdx.x * NB + b] = base;
    }
}

// Exclusive scan of the NB coarse counts (single block).
__global__ void __launch_bounds__(512) k_cscan(
        const int* __restrict__ ccnt, int* __restrict__ cstart, int NB) {
    __shared__ int s[512];
    int t = threadIdx.x;
    int c = (t < NB) ? ccnt[t * 16] : 0;
    s[t] = c;
    __syncthreads();
    for (int off = 1; off < 512; off <<= 1) {
        int v = s[t];
        int u = (t >= off) ? s[t - off] : 0;
        __syncthreads();
        s[t] = v + u;
        __syncthreads();
    }
    if (t < NB) cstart[t] = s[t] - c;
}

// Coarse scatter: same grid-stride partition as k_coarse (x4-unrolled loads),
// so this block's per-bucket totals equal its reservation. Edge packed as
// src|(dst&255)<<17.
__global__ void __launch_bounds__(256) k_cscatter(
        const int* __restrict__ ei, const int* __restrict__ fmt,
        const int* __restrict__ cstart, const int* __restrict__ blockbase,
        int* __restrict__ pairs, int E, int NB) {
    __shared__ int h[MAXNB];
    __shared__ int bb[MAXNB];
    int sh = *fmt;
    for (int i = threadIdx.x; i < NB; i += 256) {
        h[i] = 0;
        bb[i] = cstart[i] + blockbase[(long long)blockIdx.x * NB + i];
    }
    __syncthreads();
    const long long S = (long long)A1G * 256;
    long long e = (long long)blockIdx.x * 256 + threadIdx.x;
    for (; e + 3 * S < E; e += 4 * S) {
        int s0 = ei[(long long)e << sh];
        int s1 = ei[(long long)(e + S) << sh];
        int s2 = ei[(long long)(e + 2 * S) << sh];
        int s3 = ei[(long long)(e + 3 * S) << sh];
        int d0 = ei[(long long)(E + e) << sh];
        int d1 = ei[(long long)(E + e + S) << sh];
        int d2 = ei[(long long)(E + e + 2 * S) << sh];
        int d3 = ei[(long long)(E + e + 3 * S) << sh];
        int b0 = d0 >> 8, b1 = d1 >> 8, b2 = d2 >> 8, b3 = d3 >> 8;
        int r0 = atomicAdd(&h[b0], 1);
        pairs[bb[b0] + r0] = s0 | ((d0 & 255) << 17);
        int r1 = atomicAdd(&h[b1], 1);
        pairs[bb[b1] + r1] = s1 | ((d1 & 255) << 17);
        int r2 = atomicAdd(&h[b2], 1);
        pairs[bb[b2] + r2] = s2 | ((d2 & 255) << 17);
        int r3 = atomicAdd(&h[b3], 1);
        pairs[bb[b3] + r3] = s3 | ((d3 & 255) << 17);
    }
    for (; e < E; e += S) {
        int s = ei[(long long)e << sh];
        int d = ei[(long long)(E + e) << sh];
        int b = d >> 8;
        int r = atomicAdd(&h[b], 1);
        pairs[bb[b] + r] = s | ((d & 255) << 17);
    }
}

// Fine sort: one block per coarse bucket, entirely in LDS. Emits cnt/start/dis
// (coalesced) and esrc (scatter within the bucket's contiguous window).
__global__ void __launch_bounds__(256) k_bucket(
        const int* __restrict__ pairs, const int* __restrict__ ccnt,
        const int* __restrict__ cstart, int* __restrict__ esrc,
        int* __restrict__ cnt, int* __restrict__ start, float* __restrict__ dis,
        int N) {
    __shared__ int words[CAP];
    __shared__ unsigned char rk[CAP];
    __shared__ int h[NPB];
    __shared__ int hs[NPB];
    int b = blockIdx.x;
    int cs = cstart[b];
    int ec = ccnt[b * 16];
    if (ec > CAP) ec = CAP;          // memory-safety clamp (P ~ 0 for uniform dst)
    int t = threadIdx.x;
    for (int i = t; i < ec; i += 256) words[i] = pairs[cs + i];
    h[t] = 0;
    __syncthreads();
    for (int i = t; i < ec; i += 256) {
        int ld = words[i] >> 17;
        rk[i] = (unsigned char)atomicAdd(&h[ld], 1);
    }
    __syncthreads();
    int c = h[t];
    hs[t] = c;
    __syncthreads();
    for (int off = 1; off < 256; off <<= 1) {
        int v = hs[t];
        int u = (t >= off) ? hs[t - off] : 0;
        __syncthreads();
        hs[t] = v + u;               // inclusive scan
        __syncthreads();
    }
    int node = b * NPB + t;
    if (node < N) {
        cnt[node] = c;
        start[node] = cs + hs[t] - c;
        dis[node] = rsqrtf(1.0f + (float)c);   // degree includes self-loop
    }
    for (int i = t; i < ec; i += 256) {
        int w = words[i];
        int ld = w >> 17;
        esrc[cs + (hs[ld] - h[ld]) + rk[i]] = w & 0x1FFFF;
    }
}

// Shared MFMA epilogue: dis-scale + rowwise int16 quant + store.
// Lane holds D[(lane>>4)*4 + r][ct*16 + (lane&15)] for ct=0..3 (m89 map).
#define GEMM_EPILOGUE                                                         \
    int rb = (int)rowbase + wid * 16 + (lane >> 4) * 4;                       \
    float drs[4];                                                             \
    drs[0] = (rb + 0 < n) ? dis[rb + 0] : 0.0f;                               \
    drs[1] = (rb + 1 < n) ? dis[rb + 1] : 0.0f;                               \
    drs[2] = (rb + 2 < n) ? dis[rb + 2] : 0.0f;                               \
    drs[3] = (rb + 3 < n) ? dis[rb + 3] : 0.0f;                               \
    const float ks = 1.0f / 32767.0f;                                         \
    int cb = lane & 15;                                                       \
    _Pragma("unroll")                                                         \
    for (int r = 0; r < 4; ++r) {                                             \
        float v0 = acc0[r] * drs[r];                                          \
        float v1 = acc1[r] * drs[r];                                          \
        float v2 = acc2[r] * drs[r];                                          \
        float v3 = acc3[r] * drs[r];                                          \
        float m = fmaxf(fmaxf(fabsf(v0), fabsf(v1)), fmaxf(fabsf(v2), fabsf(v3))); \
        m = fmaxf(m, __shfl_xor(m, 1, 64));                                   \
        m = fmaxf(m, __shfl_xor(m, 2, 64));                                   \
        m = fmaxf(m, __shfl_xor(m, 4, 64));                                   \
        m = fmaxf(m, __shfl_xor(m, 8, 64));                                   \
        float ir = 32767.0f / fmaxf(m, 1e-20f);                               \
        int rowg = rb + r;                                                    \
        if (rowg < n) {                                                       \
            long long base = (long long)rowg * NH;                            \
            T16[base + 0  + cb] = (short)__float2int_rn(v0 * ir);             \
            T16[base + 16 + cb] = (short)__float2int_rn(v1 * ir);             \
            T16[base + 32 + cb] = (short)__float2int_rn(v2 * ir);             \
            T16[base + 48 + cb] = (short)__float2int_rn(v3 * ir);             \
            if (cb == 0) rs[rowg] = m * ks;                                   \
        }                                                                     \
    }

// Convert lane's 8 A-floats to f16 hi/lo fragments.
#define CVT_AFRAG(xa, xb4)                                                    \
    half8 ah, al;                                                             \
    {                                                                         \
        float xv[8] = {xa.x, xa.y, xa.z, xa.w, xb4.x, xb4.y, xb4.z, xb4.w};   \
        _Pragma("unroll")                                                     \
        for (int e = 0; e < 8; ++e) {                                         \
            _Float16 h = (_Float16)xv[e];                                     \
            ah[e] = h;                                                        \
            al[e] = (_Float16)(xv[e] - (float)h);                             \
        }                                                                     \
    }

#define MFMA3(ACC, SETIDX, LOHALF)                                            \
    {                                                                         \
        const half8 bh = *(const half8*)&Wf[((SETIDX) * 64 + lane) * 8];      \
        const half8 bl = *(const half8*)&Wf[((SETIDX) * 64 + lane) * 8 + (LOHALF)]; \
        ACC = __builtin_amdgcn_mfma_f32_16x16x32_f16(ah, bh, ACC, 0, 0, 0);   \
        ACC = __builtin_amdgcn_mfma_f32_16x16x32_f16(ah, bl, ACC, 0, 0, 0);   \
        ACC = __builtin_amdgcn_mfma_f32_16x16x32_f16(al, bh, ACC, 0, 0, 0);   \
    }

// Layer-0 transform on MATRIX CORES, DIRECT-LOAD A: T16 = quant(dis*(X@W0)).
// 64 rows/block, 4 waves, 16 rows/wave; lane reads its 32B A-slice per kc
// straight from global (4 lanes share each 128B line; X read exactly once).
// LDS = Wf only (32KB = 2048 int4, staged once) => 5 blocks/CU, ONE barrier.
__global__ void __launch_bounds__(256) k_gemmM(
        const float* __restrict__ X, const short* __restrict__ wfrag,
        const float* __restrict__ dis, short* __restrict__ T16,
        float* __restrict__ rs, int n) {
    __shared__ __align__(16) short Wf[16384];   // [hi 8192][lo 8192]
    int tid = threadIdx.x;
    {
        const int4* src = (const int4*)wfrag;
        int4* dst = (int4*)Wf;
        #pragma unroll
        for (int u = 0; u < 8; ++u) dst[tid + u * 256] = src[tid + u * 256];
    }
    __syncthreads();
    long long rowbase = (long long)blockIdx.x * 64;
    int lane = tid & 63;
    int wid = tid >> 6;
    int row = (int)rowbase + wid * 16 + (lane & 15);
    bool ok = row < n;
    const float* xb = X + (long long)row * NF + (lane >> 4) * 8;
    f32x4 acc0 = {0,0,0,0}, acc1 = {0,0,0,0}, acc2 = {0,0,0,0}, acc3 = {0,0,0,0};
    #pragma unroll
    for (int kc = 0; kc < 4; ++kc) {
        float4 xa = ok ? *(const float4*)(xb + kc * 32)
                       : make_float4(0.f, 0.f, 0.f, 0.f);
        float4 xc = ok ? *(const float4*)(xb + kc * 32 + 4)
                       : make_float4(0.f, 0.f, 0.f, 0.f);
        CVT_AFRAG(xa, xc)
        MFMA3(acc0, kc * 4 + 0, 8192)
        MFMA3(acc1, kc * 4 + 1, 8192)
        MFMA3(acc2, kc * 4 + 2, 8192)
        MFMA3(acc3, kc * 4 + 3, 8192)
    }
    GEMM_EPILOGUE
}

// Layer-1 transform on MATRIX CORES: T16 = quant(dis*(H0@W1)), H0 fp32 [N,64]
// streamed (coalesced GEMM operand -- r20's random-gather fp32 ban N/A).
// 24 MFMA/wave; LDS = Wf1 16KB (1024 int4).
__global__ void __launch_bounds__(256) k_gemmM64(
        const float* __restrict__ H, const short* __restrict__ wfrag,
        const float* __restrict__ dis, short* __restrict__ T16,
        float* __restrict__ rs, int n) {
    __shared__ __align__(16) short Wf[8192];    // [hi 4096][lo 4096]
    int tid = threadIdx.x;
    {
        const int4* src = (const int4*)wfrag;
        int4* dst = (int4*)Wf;
        #pragma unroll
        for (int u = 0; u < 4; ++u) dst[tid + u * 256] = src[tid + u * 256];
    }
    __syncthreads();
    long long rowbase = (long long)blockIdx.x * 64;
    int lane = tid & 63;
    int wid = tid >> 6;
    int row = (int)rowbase + wid * 16 + (lane & 15);
    bool ok = row < n;
    const float* hb = H + (long long)row * NH + (lane >> 4) * 8;
    f32x4 acc0 = {0,0,0,0}, acc1 = {0,0,0,0}, acc2 = {0,0,0,0}, acc3 = {0,0,0,0};
    #pragma unroll
    for (int kc = 0; kc < 2; ++kc) {
        float4 xa = ok ? *(const float4*)(hb + kc * 32)
                       : make_float4(0.f, 0.f, 0.f, 0.f);
        float4 xc = ok ? *(const float4*)(hb + kc * 32 + 4)
                       : make_float4(0.f, 0.f, 0.f, 0.f);
        CVT_AFRAG(xa, xc)
        MFMA3(acc0, kc * 4 + 0, 4096)
        MFMA3(acc1, kc * 4 + 1, 4096)
        MFMA3(acc2, kc * 4 + 2, 4096)
        MFMA3(acc3, kc * 4 + 3, 4096)
    }
    GEMM_EPILOGUE
}

// One A-edge / B-edge step: readlane word+scale bits, saddr int16 load, fma.
#define EDGE_A(J) {                                                           \
    int s_ = __builtin_amdgcn_readlane(sA, (J));                              \
    float f_ = __int_as_float(__builtin_amdgcn_readlane(fAb, (J)));           \
    accA = fmaf(f_, (float)(T + s_ * NH)[lane], accA); }
#define EDGE_B(J) {                                                           \
    int s_ = __builtin_amdgcn_readlane(sB, (J));                              \
    float f_ = __int_as_float(__builtin_amdgcn_readlane(fBb, (J)));           \
    accB = fmaf(f_, (float)(T + s_ * NH)[lane], accB); }

// Full-wave gather, TWO nodes per wave (A,B) with interleaved batches:
// the two batch prologues (esrc load + rs vector-gather) are independent
// chains and overlap; inner loop interleaves 4 A-edges + 4 B-edges.
#define SEG_GATHER2                                                           \
    int lane = threadIdx.x & 63;                                              \
    int na = blockIdx.x * 8 + (threadIdx.x >> 6) * 2;                         \
    int nb_ = na + 1;                                                         \
    if (na >= n) return;                                                      \
    bool hasB = (nb_ < n);                                                    \
    float dia = dis[na];                                                      \
    float dib = hasB ? dis[nb_] : 0.0f;                                       \
    int ga = cnt[na], sta = start[na];                                        \
    int gb = hasB ? cnt[nb_] : 0;                                             \
    int stb = hasB ? start[nb_] : 0;                                          \
    float accA = rs[na] * (float)T[na * NH + lane];                           \
    float accB = hasB ? rs[nb_] * (float)T[nb_ * NH + lane] : 0.0f;           \
    int gmax = ga > gb ? ga : gb;                                             \
    for (int base = 0; base < gmax; base += 64) {                             \
        int ma = ga - base; ma = ma < 0 ? 0 : (ma > 64 ? 64 : ma);            \
        int mb = gb - base; mb = mb < 0 ? 0 : (mb > 64 ? 64 : mb);            \
        int sA = 0, sB = 0; float fA = 0.0f, fB = 0.0f;                       \
        if (lane < ma) { sA = esrc[sta + base + lane]; fA = rs[sA]; }         \
        if (lane < mb) { sB = esrc[stb + base + lane]; fB = rs[sB]; }         \
        int fAb = __float_as_int(fA), fBb = __float_as_int(fB);               \
        int mmin = ma < mb ? ma : mb;                                         \
        int j = 0;                                                            \
        for (; j + 3 < mmin; j += 4) {                                        \
            EDGE_A(j + 0) EDGE_B(j + 0)                                       \
            EDGE_A(j + 1) EDGE_B(j + 1)                                       \
            EDGE_A(j + 2) EDGE_B(j + 2)                                       \
            EDGE_A(j + 3) EDGE_B(j + 3)                                       \
        }                                                                     \
        int jA = j, jB = j;                                                   \
        for (; jA + 3 < ma; jA += 4) {                                        \
            EDGE_A(jA + 0) EDGE_A(jA + 1) EDGE_A(jA + 2) EDGE_A(jA + 3)       \
        }                                                                     \
        for (; jA < ma; ++jA) EDGE_A(jA)                                      \
        for (; jB + 3 < mb; jB += 4) {                                        \
            EDGE_B(jB + 0) EDGE_B(jB + 1) EDGE_B(jB + 2) EDGE_B(jB + 3)       \
        }                                                                     \
        for (; jB < mb; ++jB) EDGE_B(jB)                                      \
    }

// Layer-0 aggregation: h0 = dia*acc + b0 written as fp32 (streamed GEMM
// operand for k_gemmM64). r2-verified form (~46us, VALUBusy 73%, occ 72%).
__global__ void __launch_bounds__(256) k_seg(
        const short* __restrict__ T, const float* __restrict__ rs,
        const int* __restrict__ esrc, const int* __restrict__ start,
        const int* __restrict__ cnt, const float* __restrict__ dis,
        const float* __restrict__ b0, float* __restrict__ O, int n) {
    SEG_GATHER2
    float bv = b0[lane];
    O[(long long)na * NH + lane] = dia * accA + bv;
    if (hasB) O[(long long)nb_ * NH + lane] = dib * accB + bv;
}

// Layer-1 + fused layer-2 transform for both nodes: z1[c]=di*acc+b1[c];
// t=tanh(z1); t2 = di*(t @ W2) via 6-step full-wave butterfly (per node).
__global__ void __launch_bounds__(256) k_seg1f(
        const short* __restrict__ T, const float* __restrict__ rs,
        const int* __restrict__ esrc, const int* __restrict__ start,
        const int* __restrict__ cnt, const float* __restrict__ dis,
        const float* __restrict__ b1, const float* __restrict__ W2,
        float2* __restrict__ t2, int n) {
    SEG_GATHER2
    float bv = b1[lane];
    float2 w = ((const float2*)W2)[lane];   // W2[lane][0], W2[lane][1]
    float tA = tanhf(dia * accA + bv);
    float p0 = tA * w.x, p1 = tA * w.y;
    float tB = hasB ? tanhf(dib * accB + bv) : 0.0f;
    float q0 = tB * w.x, q1 = tB * w.y;
    #pragma unroll
    for (int msk = 32; msk; msk >>= 1) {
        p0 += __shfl_xor(p0, msk, 64);
        p1 += __shfl_xor(p1, msk, 64);
        q0 += __shfl_xor(q0, msk, 64);
        q1 += __shfl_xor(q1, msk, 64);
    }
    if (lane == 0) {
        t2[na] = make_float2(dia * p0, dia * p1);
        if (hasB) t2[nb_] = make_float2(dib * q0, dib * q1);
    }
}

// Fused layer-2 aggregation + head, 16 LANES PER NODE (4 nodes/wave):
// lane-parallel edge loads, 4-step shfl_xor reduce, lanes 0-3 write the
// 16 output channels.
__global__ void __launch_bounds__(256) k_seg2f(
        const float2* __restrict__ T2, const int* __restrict__ esrc,
        const int* __restrict__ start, const int* __restrict__ cnt,
        const float* __restrict__ dis, const float* __restrict__ b2,
        const float* __restrict__ Wc, const float* __restrict__ bc,
        float* __restrict__ out, float* __restrict__ emb, int n) {
    int lane = threadIdx.x & 63;
    int sub = lane >> 4;           // node slot within the wave
    int sl = lane & 15;            // lane within the node's 16-lane group
    int i = blockIdx.x * 16 + (threadIdx.x >> 6) * 4 + sub;
    if (i >= n) return;            // whole 16-lane group exits together
    float di = dis[i];
    int g = cnt[i], st = start[i];
    float a0 = 0.0f, a1 = 0.0f;
    for (int j = sl; j < g; j += 16) {
        float2 v = T2[esrc[st + j]];
        a0 += v.x; a1 += v.y;
    }
    if (sl == 0) {
        float2 s = T2[i];
        a0 += s.x; a1 += s.y;
    }
    #pragma unroll
    for (int msk = 8; msk; msk >>= 1) {
        a0 += __shfl_xor(a0, msk, 64);
        a1 += __shfl_xor(a1, msk, 64);
    }
    float e0 = tanhf(a0 * di + b2[0]);
    float e1 = tanhf(a1 * di + b2[1]);
    if (sl == 0) *(float2*)&emb[(long long)i * 2] = make_float2(e0, e1);
    if (sl < 4) {
        int c = sl * 4;
        float4 o;
        o.x = e0 * Wc[c + 0] + e1 * Wc[16 + c + 0] + bc[c + 0];
        o.y = e0 * Wc[c + 1] + e1 * Wc[16 + c + 1] + bc[c + 1];
        o.z = e0 * Wc[c + 2] + e1 * Wc[16 + c + 2] + bc[c + 2];
        o.w = e0 * Wc[c + 3] + e1 * Wc[16 + c + 3] + bc[c + 3];
        *(float4*)&out[(long long)i * 16 + c] = o;
    }
}

extern "C" void kernel_launch(void* const* d_in, const int* in_sizes, int n_in,
                              void* d_out, int out_size, void* d_ws, size_t ws_size,
                              hipStream_t stream) {
    const float* x  = (const float*)d_in[0];
    const int*   ei = (const int*)  d_in[1];
    const float* W0 = (const float*)d_in[2];
    const float* b0 = (const float*)d_in[3];
    const float* W1 = (const float*)d_in[4];
    const float* b1 = (const float*)d_in[5];
    const float* W2 = (const float*)d_in[6];
    const float* b2 = (const float*)d_in[7];
    const float* Wc = (const float*)d_in[8];
    const float* bc = (const float*)d_in[9];

    int N = in_sizes[0] / NF;
    int E = in_sizes[1] / 2;
    int NB = (N + NPB - 1) / NPB;   // 391 for N=100000 (must be <= MAXNB)

    float* out = (float*)d_out;                    // [N,16]
    float* emb = out + (long long)N * 16;          // [N,2]

    // workspace (UNCHANGED footprint vs verified rounds):
    //   T16a[N*64 int16 = 12.8MB] | Bb[N*64 fp32 = 25.6MB] |
    //   dis[N] | rs_a[N] | cnt[N] | start[N] | esrc[E] | fmt
    // wf0 (32KB) + wf1 (16KB) live at the START OF d_out: out is written
    // only by the final k_seg2f (which overwrites every element); fragments
    // are consumed by gemmM/gemmM64 before that. Zero footprint growth.
    // Flow: gemmM: x->T16a.  k_seg: T16a->Bb (h0).  gemmM64: Bb->T16a.
    // seg1f: T16a->t2 (t2 overlays dead Bb).  Prep scratch overlays T16a.
    short*  T16a = (short*)d_ws;
    float*  Bb   = (float*)((char*)d_ws + (long long)N * NH * 2);
    float*  dis  = (float*)((char*)d_ws + (long long)N * NH * 2 + (long long)N * NH * 4);
    float*  rs_a = dis + N;
    int*    cnt   = (int*)(rs_a + N);
    int*    start = cnt + N;
    int*    esrc  = start + N;
    int*    fmt   = esrc + E;
    short*  wf0   = (short*)d_out;                 // 16384 shorts (32KB)
    short*  wf1   = wf0 + 16384;                   // 8192 shorts (16KB)
    float2* t2    = (float2*)Bb;                   // overlays dead Bb

    int* pairs     = (int*)d_ws;                       // E ints (overlay T16a)
    int* blockbase = pairs + E;                        // A1G * NB
    int* ccnt      = blockbase + (long long)A1G * NB;  // NB*16 (line-padded)
    int* cstart    = ccnt + NB * 16;                   // NB

    int nb_g  = (N + 63) / 64;
    int nb_s2 = (N + 7) / 8;
    int nb_2f = (N + 15) / 16;
    int nb16  = NB * 16;
    int nb_i0 = (nb16 + 255) / 256;

    // merged: W fragments + ccnt zero + fmt detect
    k_prep0   <<<24 + nb_i0, 256, 0, stream>>>(W0, W1, wf0, wf1, ei, fmt,
                                               ccnt, nb16);
    // per-call two-level bucket sort (inputs restored before every call)
    k_coarse  <<<A1G, 256, 0, stream>>>(ei, fmt, ccnt, blockbase, E, NB);
    k_cscan   <<<1, 512, 0, stream>>>(ccnt, cstart, NB);
    k_cscatter<<<A1G, 256, 0, stream>>>(ei, fmt, cstart, blockbase, pairs, E, NB);
    k_bucket  <<<NB, 256, 0, stream>>>(pairs, ccnt, cstart, esrc, cnt, start, dis, N);

    // layer 0: MFMA gemm (direct-load A) + rowwise int16 quant
    k_gemmM   <<<nb_g, 256, 0, stream>>>(x, wf0, dis, T16a, rs_a, N);

    // layer-0 gather -> h0 fp32 (streamed operand)
    k_seg     <<<nb_s2, 256, 0, stream>>>(T16a, rs_a, esrc, start, cnt, dis, b0,
                                          Bb, N);

    // layer-1 transform: MFMA gemm64 (Bb -> T16a, rs_a overwritten)
    k_gemmM64 <<<nb_g, 256, 0, stream>>>(Bb, wf1, dis, T16a, rs_a, N);

    // layer 1 gather + fused layer-2 transform (tanh + @W2 in epilogue)
    k_seg1f   <<<nb_s2, 256, 0, stream>>>(T16a, rs_a, esrc, start, cnt, dis, b1,
                                          W2, t2, N);

    // layer-2 aggregation + head (16 lanes per node)
    k_seg2f   <<<nb_2f, 256, 0, stream>>>(t2, esrc, start, cnt, dis, b2, Wc, bc,
                                          out, emb, N);
}